// Round 15
// baseline (34.395 us; speedup 1.0000x reference)
//
#include <hip/hip_runtime.h>

#define G 7
#define CCH 256
#define NLVL 6

__device__ __constant__ int kD[NLVL]  = {38, 19, 10, 5, 3, 1};
__device__ __constant__ int kD2[NLVL] = {1444, 361, 100, 25, 9, 1};
// base offset (in floats) of each level inside the transposed fmap buffer
__device__ __constant__ int kBaseT[NLVL + 1] = {0, 369664, 462080, 487680, 494080, 496384, 496640};

#define FMT_TOTAL 496640  // floats

// ---------------- kernel 1: transpose fmaps [C][D*D] -> [D*D][C] ----------------
__global__ __launch_bounds__(256) void transpose_fmaps(
    const float* __restrict__ f0, const float* __restrict__ f1,
    const float* __restrict__ f2, const float* __restrict__ f3,
    const float* __restrict__ f4, const float* __restrict__ f5,
    float* __restrict__ fmT)
{
    int o = blockIdx.x * blockDim.x + threadIdx.x;
    if (o >= FMT_TOTAL) return;
    int l = 0;
#pragma unroll
    for (int k = 1; k < NLVL; ++k) l += (o >= kBaseT[k]);
    int rel = o - kBaseT[l];
    int p = rel >> 8;        // position within D*D
    int c = rel & 255;       // channel
    const float* f;
    switch (l) {
        case 0: f = f0; break;
        case 1: f = f1; break;
        case 2: f = f2; break;
        case 3: f = f3; break;
        case 4: f = f4; break;
        default: f = f5; break;
    }
    fmT[o] = f[c * kD2[l] + p];
}

// ---------------- kernel 2: one block per box; small slabs, 4 passes/wave ----------------
__global__ __launch_bounds__(256) void roialign_main(
    const float* __restrict__ boxes, const float* __restrict__ fmT,
    float* __restrict__ out)
{
    __shared__ float slab[4][784];     // 3136 B per wave (16 ch x 49 g)

    int n = blockIdx.x;
    int tid = threadIdx.x;
    int wv = tid >> 6;
    int lane = tid & 63;
    int cl = lane & 15;                // channel-local 0..15
    int q  = lane >> 4;                // i-group 0..3

    // box params (uniform; redundant per-lane compute is cheap)
    float bx1 = boxes[n * 4 + 0];
    float by1 = boxes[n * 4 + 1];
    float bx2 = boxes[n * 4 + 2];
    float by2 = boxes[n * 4 + 3];
    float w = bx2 - bx1;
    float h = by2 - by1;
    // level: clip(floor(5 + log2(sqrt(w*h))), 0, 5), same f32 op order as ref
    float avg = sqrtf(w * h);
    float lf = floorf((float)(NLVL - 1) + log2f(avg));
    lf = fminf(fmaxf(lf, 0.0f), (float)(NLVL - 1));
    int lvl = __builtin_amdgcn_readfirstlane((int)lf);   // scalarize
    int D    = kD[lvl];
    int base = kBaseT[lvl];
    float Dm1 = (float)(D - 1);
    int Dm1i = D - 1;
    int Drow = D << 8;                 // D * CCH (floats)

    float* ms = slab[wv];
    size_t boxBase = (size_t)n * (CCH * G * G);

#pragma unroll
    for (int hh = 0; hh < 4; ++hh) {
        int c = wv * 64 + hh * 16 + cl;
        int bt = base + c;

        // lane (cl,q) computes rows i = q and i = q+4 (q<3), all 7 j's
#pragma unroll
        for (int r = 0; r < 2; ++r) {
            int i = q + 4 * r;
            if (r == 0 || q < 3) {
                // exact reference op order: clip(x1 + i*(x2-x1)/6, 0, 1)
                float xr = fminf(fmaxf(bx1 + ((float)i * w) / 6.0f, 0.0f), 1.0f);
                float ux = xr * Dm1;
                float xf = floorf(ux);
                float fx = ux - xf;            // px1
                int ix0 = (int)xf;
                int oxa = ix0 * Drow;
                int oxb = oxa + ((ix0 < Dm1i) ? Drow : 0);
                float px0 = 1.0f - fx;
                int rb = cl * 49 + i * 7;
#pragma unroll
                for (int j = 0; j < 7; ++j) {
                    float yr = fminf(fmaxf(by1 + ((float)j * h) / 6.0f, 0.0f), 1.0f);
                    float uy = yr * Dm1;
                    float yf = floorf(uy);
                    float fy = uy - yf;        // py1
                    int iy0 = (int)yf;
                    int oya = iy0 << 8;        // iy0 * CCH
                    int oyb = oya + ((iy0 < Dm1i) ? 256 : 0);
                    float a00 = fmT[bt + oxa + oya];
                    float a10 = fmT[bt + oxb + oya];
                    float a01 = fmT[bt + oxa + oyb];
                    float a11 = fmT[bt + oxb + oyb];
                    float vx0 = px0 * a00 + fx * a10;   // x-interp at y0
                    float vx1 = px0 * a01 + fx * a11;   // x-interp at y1
                    ms[rb + j] = (1.0f - fy) * vx0 + fy * vx1;
                    // bank = (17*cl + 7*q) mod 32: exactly 2-way -> free
                }
            }
        }

        // wave-local DS ordering (cross-lane read of this wave's own writes):
        // explicit wait + scheduling fence required (rule #18).
        asm volatile("s_waitcnt lgkmcnt(0)" ::: "memory");
        __builtin_amdgcn_sched_barrier(0);

        // store burst: this pass's 16ch x 49g chunk, dense float4 (3136 B)
        const float4* s4 = (const float4*)ms;
        float4* out4 = (float4*)(out + boxBase) + (wv * 784 + hh * 196);
        out4[lane]       = s4[lane];
        out4[64 + lane]  = s4[64 + lane];
        out4[128 + lane] = s4[128 + lane];
        if (lane < 4) out4[192 + lane] = s4[192 + lane];   // 196 = 3*64 + 4
        // next pass's ds_writes can't pass these ds_reads (same-wave DS in-order)
    }
}

// ---------------- fallback (round-2 kernel) if ws too small ----------------
__global__ __launch_bounds__(256) void roialign_fallback(
    const float* __restrict__ boxes,
    const float* __restrict__ f0, const float* __restrict__ f1,
    const float* __restrict__ f2, const float* __restrict__ f3,
    const float* __restrict__ f4, const float* __restrict__ f5,
    float* __restrict__ out, int total4)
{
    int t = blockIdx.x * blockDim.x + threadIdx.x;
    if (t >= total4) return;
    const int perN = CCH * G * G;
    int idx = t * 4;
    int n = idx / perN;
    int rem = idx - n * perN;
    float bx1 = boxes[n * 4 + 0], by1 = boxes[n * 4 + 1];
    float bx2 = boxes[n * 4 + 2], by2 = boxes[n * 4 + 3];
    float w = bx2 - bx1, h = by2 - by1;
    float avg = sqrtf(w * h);
    float lf = floorf((float)(NLVL - 1) + log2f(avg));
    lf = fminf(fmaxf(lf, 0.0f), (float)(NLVL - 1));
    int lvl = (int)lf;
    const float* fm;
    switch (lvl) {
        case 0: fm = f0; break;
        case 1: fm = f1; break;
        case 2: fm = f2; break;
        case 3: fm = f3; break;
        case 4: fm = f4; break;
        default: fm = f5; break;
    }
    int D = kD[lvl];
    float Dm1 = (float)(D - 1);
    float4 res;
    float* rp = &res.x;
#pragma unroll
    for (int k = 0; k < 4; ++k) {
        int e = rem + k;
        int j = e % G;
        int iq = e / G;
        int i = iq % G;
        int c = iq / G;
        float xr = fminf(fmaxf(bx1 + ((float)i * w) / 6.0f, 0.0f), 1.0f);
        float yr = fminf(fmaxf(by1 + ((float)j * h) / 6.0f, 0.0f), 1.0f);
        float ux = xr * Dm1, uy = yr * Dm1;
        float x0 = floorf(ux), y0 = floorf(uy);
        int ix0 = (int)x0, iy0 = (int)y0;
        float fx = ux - x0, fy = uy - y0;
        int ix1 = min(ix0 + 1, D - 1), iy1 = min(iy0 + 1, D - 1);
        const float* p = fm + c * D * D;
        float v00 = p[ix0 * D + iy0], v10 = p[ix1 * D + iy0];
        float v01 = p[ix0 * D + iy1], v11 = p[ix1 * D + iy1];
        float px0 = 1.0f - fx, py0 = 1.0f - fy;
        rp[k] = px0 * py0 * v00 + fx * py0 * v10 + px0 * fy * v01 + fx * fy * v11;
    }
    reinterpret_cast<float4*>(out)[t] = res;
}

extern "C" void kernel_launch(void* const* d_in, const int* in_sizes, int n_in,
                              void* d_out, int out_size, void* d_ws, size_t ws_size,
                              hipStream_t stream) {
    const float* boxes = (const float*)d_in[0];
    const float* f0 = (const float*)d_in[1];
    const float* f1 = (const float*)d_in[2];
    const float* f2 = (const float*)d_in[3];
    const float* f3 = (const float*)d_in[4];
    const float* f4 = (const float*)d_in[5];
    const float* f5 = (const float*)d_in[6];
    float* out = (float*)d_out;
    int N = in_sizes[0] / 4;

    if (ws_size >= (size_t)FMT_TOTAL * sizeof(float)) {
        float* fmT = (float*)d_ws;
        transpose_fmaps<<<(FMT_TOTAL + 255) / 256, 256, 0, stream>>>(
            f0, f1, f2, f3, f4, f5, fmT);
        roialign_main<<<N, 256, 0, stream>>>(boxes, fmT, out);
    } else {
        int total4 = out_size / 4;
        roialign_fallback<<<(total4 + 255) / 256, 256, 0, stream>>>(
            boxes, f0, f1, f2, f3, f4, f5, out, total4);
    }
}

// Round 17
// 29.995 us; speedup vs baseline: 1.1467x; 1.1467x over previous
//
#include <hip/hip_runtime.h>

#define G 7
#define CCH 256
#define NLVL 6

typedef float vfloat4 __attribute__((ext_vector_type(4)));   // native vec for NT builtins

__device__ __constant__ int kD[NLVL]  = {38, 19, 10, 5, 3, 1};
__device__ __constant__ int kD2[NLVL] = {1444, 361, 100, 25, 9, 1};
// base offset (in floats) of each level inside the transposed fmap buffer
__device__ __constant__ int kBaseT[NLVL + 1] = {0, 369664, 462080, 487680, 494080, 496384, 496640};

#define FMT_TOTAL 496640  // floats

// ---------------- kernel 1: transpose fmaps [C][D*D] -> [D*D][C] ----------------
__global__ __launch_bounds__(256) void transpose_fmaps(
    const float* __restrict__ f0, const float* __restrict__ f1,
    const float* __restrict__ f2, const float* __restrict__ f3,
    const float* __restrict__ f4, const float* __restrict__ f5,
    float* __restrict__ fmT)
{
    int o = blockIdx.x * blockDim.x + threadIdx.x;
    if (o >= FMT_TOTAL) return;
    int l = 0;
#pragma unroll
    for (int k = 1; k < NLVL; ++k) l += (o >= kBaseT[k]);
    int rel = o - kBaseT[l];
    int p = rel >> 8;        // position within D*D
    int c = rel & 255;       // channel
    const float* f;
    switch (l) {
        case 0: f = f0; break;
        case 1: f = f1; break;
        case 2: f = f2; break;
        case 3: f = f3; break;
        case 4: f = f4; break;
        default: f = f5; break;
    }
    fmT[o] = f[c * kD2[l] + p];
}

// ---------------- kernel 2: one block per box; table-free; NT writeback ----------------
__global__ __launch_bounds__(256) void roialign_main(
    const float* __restrict__ boxes, const float* __restrict__ fmT,
    float* __restrict__ out)
{
    __shared__ float sOut[CCH * 49];   // [c][g]; wave w owns rows 64w..64w+63

    int n = blockIdx.x;
    int tid = threadIdx.x;             // == channel c

    // box params (wave-uniform; all lanes compute redundantly — VALU is cheap)
    float bx1 = boxes[n * 4 + 0];
    float by1 = boxes[n * 4 + 1];
    float bx2 = boxes[n * 4 + 2];
    float by2 = boxes[n * 4 + 3];
    float w = bx2 - bx1;
    float h = by2 - by1;
    // level: clip(floor(5 + log2(sqrt(w*h))), 0, 5), same f32 op order as ref
    float avg = sqrtf(w * h);
    float lf = floorf((float)(NLVL - 1) + log2f(avg));
    lf = fminf(fmaxf(lf, 0.0f), (float)(NLVL - 1));
    int lvl = __builtin_amdgcn_readfirstlane((int)lf);   // scalarize
    int D    = kD[lvl];
    int base = kBaseT[lvl];
    float Dm1 = (float)(D - 1);
    int Dm1i = D - 1;
    int Drow = D << 8;                 // D * CCH
    float w6 = w * (1.0f / 6.0f);
    float h6 = h * (1.0f / 6.0f);
    int baset = base + tid;            // fold channel into the cell offset

    float* row = sOut + tid * 49;      // bank = (49*tid)%32: permutation, conflict-free

    // ---- gather/FMA: per-g cell+weights recomputed in VALU (i,j constexpr) ----
#pragma unroll
    for (int g = 0; g < 49; ++g) {
        const int i = g / 7;
        const int j = g - 7 * i;
        float xr = fminf(fmaxf(fmaf((float)i, w6, bx1), 0.0f), 1.0f);
        float yr = fminf(fmaxf(fmaf((float)j, h6, by1), 0.0f), 1.0f);
        float ux = xr * Dm1;
        float uy = yr * Dm1;
        float xf = floorf(ux);
        float yf = floorf(uy);
        float fx = ux - xf;            // px1
        float fy = uy - yf;            // py1
        int ix0 = (int)xf;
        int iy0 = (int)yf;
        int o00 = baset + ((ix0 * D + iy0) << 8);
        int dxo = (ix0 < Dm1i) ? Drow : 0;   // min(ix0+1, D-1) as an offset delta
        int dyo = (iy0 < Dm1i) ? 256 : 0;
        float a00 = fmT[o00];
        float a10 = fmT[o00 + dxo];
        float a01 = fmT[o00 + dyo];
        float a11 = fmT[o00 + dxo + dyo];
        float px0 = 1.0f - fx, py0 = 1.0f - fy;
        float vx0 = px0 * a00 + fx * a10;    // x-interp at y0
        float vx1 = px0 * a01 + fx * a11;    // x-interp at y1
        row[g] = py0 * vx0 + fy * vx1;
    }

    // wave-local DS ordering: readback below reads rows written by lanes of THIS
    // wave only (cross-lane, same wave). Compiler can't see the cross-lane dep;
    // explicit wait + scheduling fence required (rule #18).
    asm volatile("s_waitcnt lgkmcnt(0)" ::: "memory");
    __builtin_amdgcn_sched_barrier(0);

    // ---- writeback: wave streams its slab; NON-TEMPORAL (bypass L2 alloc) ----
    int wv_id = tid >> 6;
    int lane = tid & 63;
    const vfloat4* s4 = (const vfloat4*)sOut + wv_id * 784;
    vfloat4* out4 = (vfloat4*)(out + (size_t)n * (CCH * G * G)) + wv_id * 784;
#pragma unroll
    for (int k = 0; k < 12; ++k) {
        __builtin_nontemporal_store(s4[k * 64 + lane], &out4[k * 64 + lane]);
    }
    if (lane < 16) {
        __builtin_nontemporal_store(s4[768 + lane], &out4[768 + lane]);  // 784 = 12*64+16
    }
}

// ---------------- fallback (round-2 kernel) if ws too small ----------------
__global__ __launch_bounds__(256) void roialign_fallback(
    const float* __restrict__ boxes,
    const float* __restrict__ f0, const float* __restrict__ f1,
    const float* __restrict__ f2, const float* __restrict__ f3,
    const float* __restrict__ f4, const float* __restrict__ f5,
    float* __restrict__ out, int total4)
{
    int t = blockIdx.x * blockDim.x + threadIdx.x;
    if (t >= total4) return;
    const int perN = CCH * G * G;
    int idx = t * 4;
    int n = idx / perN;
    int rem = idx - n * perN;
    float bx1 = boxes[n * 4 + 0], by1 = boxes[n * 4 + 1];
    float bx2 = boxes[n * 4 + 2], by2 = boxes[n * 4 + 3];
    float w = bx2 - bx1, h = by2 - by1;
    float avg = sqrtf(w * h);
    float lf = floorf((float)(NLVL - 1) + log2f(avg));
    lf = fminf(fmaxf(lf, 0.0f), (float)(NLVL - 1));
    int lvl = (int)lf;
    const float* fm;
    switch (lvl) {
        case 0: fm = f0; break;
        case 1: fm = f1; break;
        case 2: fm = f2; break;
        case 3: fm = f3; break;
        case 4: fm = f4; break;
        default: fm = f5; break;
    }
    int D = kD[lvl];
    float Dm1 = (float)(D - 1);
    float4 res;
    float* rp = &res.x;
#pragma unroll
    for (int k = 0; k < 4; ++k) {
        int e = rem + k;
        int j = e % G;
        int iq = e / G;
        int i = iq % G;
        int c = iq / G;
        float xr = fminf(fmaxf(bx1 + ((float)i * w) / 6.0f, 0.0f), 1.0f);
        float yr = fminf(fmaxf(by1 + ((float)j * h) / 6.0f, 0.0f), 1.0f);
        float ux = xr * Dm1, uy = yr * Dm1;
        float x0 = floorf(ux), y0 = floorf(uy);
        int ix0 = (int)x0, iy0 = (int)y0;
        float fx = ux - x0, fy = uy - y0;
        int ix1 = min(ix0 + 1, D - 1), iy1 = min(iy0 + 1, D - 1);
        const float* p = fm + c * D * D;
        float v00 = p[ix0 * D + iy0], v10 = p[ix1 * D + iy0];
        float v01 = p[ix0 * D + iy1], v11 = p[ix1 * D + iy1];
        float px0 = 1.0f - fx, py0 = 1.0f - fy;
        rp[k] = px0 * py0 * v00 + fx * py0 * v10 + px0 * fy * v01 + fx * fy * v11;
    }
    reinterpret_cast<float4*>(out)[t] = res;
}

extern "C" void kernel_launch(void* const* d_in, const int* in_sizes, int n_in,
                              void* d_out, int out_size, void* d_ws, size_t ws_size,
                              hipStream_t stream) {
    const float* boxes = (const float*)d_in[0];
    const float* f0 = (const float*)d_in[1];
    const float* f1 = (const float*)d_in[2];
    const float* f2 = (const float*)d_in[3];
    const float* f3 = (const float*)d_in[4];
    const float* f4 = (const float*)d_in[5];
    const float* f5 = (const float*)d_in[6];
    float* out = (float*)d_out;
    int N = in_sizes[0] / 4;

    if (ws_size >= (size_t)FMT_TOTAL * sizeof(float)) {
        float* fmT = (float*)d_ws;
        transpose_fmaps<<<(FMT_TOTAL + 255) / 256, 256, 0, stream>>>(
            f0, f1, f2, f3, f4, f5, fmT);
        roialign_main<<<N, 256, 0, stream>>>(boxes, fmT, out);
    } else {
        int total4 = out_size / 4;
        roialign_fallback<<<(total4 + 255) / 256, 256, 0, stream>>>(
            boxes, f0, f1, f2, f3, f4, f5, out, total4);
    }
}

// Round 18
// 29.425 us; speedup vs baseline: 1.1689x; 1.0194x over previous
//
#include <hip/hip_runtime.h>

#define G 7
#define CCH 256
#define NLVL 6

typedef float vfloat4 __attribute__((ext_vector_type(4)));   // native vec for NT builtins

__device__ __constant__ int kD[NLVL]  = {38, 19, 10, 5, 3, 1};
__device__ __constant__ int kD2[NLVL] = {1444, 361, 100, 25, 9, 1};
// base offset (in floats) of each level inside the transposed fmap buffer
__device__ __constant__ int kBaseT[NLVL + 1] = {0, 369664, 462080, 487680, 494080, 496384, 496640};

#define FMT_TOTAL 496640  // floats

// readlane helpers (readlane builtin is i32)
#define RL_F(v, l) __builtin_bit_cast(float, __builtin_amdgcn_readlane(__builtin_bit_cast(int, (v)), (l)))
#define RL_I(v, l) __builtin_amdgcn_readlane((v), (l))

// ---------------- kernel 1: transpose fmaps [C][D*D] -> [D*D][C] ----------------
__global__ __launch_bounds__(256) void transpose_fmaps(
    const float* __restrict__ f0, const float* __restrict__ f1,
    const float* __restrict__ f2, const float* __restrict__ f3,
    const float* __restrict__ f4, const float* __restrict__ f5,
    float* __restrict__ fmT)
{
    int o = blockIdx.x * blockDim.x + threadIdx.x;
    if (o >= FMT_TOTAL) return;
    int l = 0;
#pragma unroll
    for (int k = 1; k < NLVL; ++k) l += (o >= kBaseT[k]);
    int rel = o - kBaseT[l];
    int p = rel >> 8;        // position within D*D
    int c = rel & 255;       // channel
    const float* f;
    switch (l) {
        case 0: f = f0; break;
        case 1: f = f1; break;
        case 2: f = f2; break;
        case 3: f = f3; break;
        case 4: f = f4; break;
        default: f = f5; break;
    }
    fmT[o] = f[c * kD2[l] + p];
}

// ---------------- kernel 2: hoisted-scalar params; SALU addressing; NT writeback ----------------
__global__ __launch_bounds__(256) void roialign_main(
    const float* __restrict__ boxes, const float* __restrict__ fmT,
    float* __restrict__ out)
{
    __shared__ float sOut[CCH * 49];   // [c][g]; wave w owns rows 64w..64w+63

    int n = blockIdx.x;
    int tid = threadIdx.x;             // == channel c
    int lane = tid & 63;

    // box params (uniform)
    float bx1 = boxes[n * 4 + 0];
    float by1 = boxes[n * 4 + 1];
    float bx2 = boxes[n * 4 + 2];
    float by2 = boxes[n * 4 + 3];
    float w = bx2 - bx1;
    float h = by2 - by1;
    // level: clip(floor(5 + log2(sqrt(w*h))), 0, 5), same f32 op order as ref
    float avg = sqrtf(w * h);
    float lf = floorf((float)(NLVL - 1) + log2f(avg));
    lf = fminf(fmaxf(lf, 0.0f), (float)(NLVL - 1));
    int lvl = __builtin_amdgcn_readfirstlane((int)lf);   // scalarize
    int D    = kD[lvl];
    int base = kBaseT[lvl];
    float Dm1 = (float)(D - 1);
    int Dm1i = D - 1;
    int Drow = D << 8;                 // D * CCH (floats)

    // ---- lane-parallel separable params: lane t computes the t-th i/j params ----
    // (valid for lane<7; other lanes compute clipped garbage, never read)
    float t = (float)lane;
    // exact reference op order: clip(x1 + t*(x2-x1)/6, 0, 1)
    float xr = fminf(fmaxf(bx1 + (t * w) / 6.0f, 0.0f), 1.0f);
    float ux = xr * Dm1;
    float xf = floorf(ux);
    float fxv = ux - xf;               // px1
    int ix0 = (int)xf;
    int xoAv = ix0 * Drow;
    int xoBv = xoAv + ((ix0 < Dm1i) ? Drow : 0);
    float xpAv = 1.0f - fxv;           // px0

    float yr = fminf(fmaxf(by1 + (t * h) / 6.0f, 0.0f), 1.0f);
    float uy = yr * Dm1;
    float yf = floorf(uy);
    float fyv = uy - yf;               // py1
    int iy0 = (int)yf;
    int yoAv = iy0 << 8;               // iy0 * CCH
    int yoBv = yoAv + ((iy0 < Dm1i) ? 256 : 0);
    float ypAv = 1.0f - fyv;           // py0

    // ---- hoist ALL readlanes ONCE (56 instrs, amortized over 49 g's) ----
    float xwA[7], xwB[7], ywA[7], ywB[7];
    int   xoA[7], xoB[7], yoA[7], yoB[7];
#pragma unroll
    for (int k = 0; k < 7; ++k) {
        xwA[k] = RL_F(xpAv, k);
        xwB[k] = RL_F(fxv, k);
        xoA[k] = RL_I(xoAv, k);
        xoB[k] = RL_I(xoBv, k);
        ywA[k] = RL_F(ypAv, k);
        ywB[k] = RL_F(fyv, k);
        yoA[k] = RL_I(yoAv, k);
        yoB[k] = RL_I(yoBv, k);
    }

    const float* fmB = fmT + base;     // uniform
    float* row = sOut + tid * 49;      // bank = (49*tid)%32: permutation, conflict-free

    // ---- gather/FMA: per-g = SALU pointer combine + 4 saddr loads + 6 FMA ----
#pragma unroll
    for (int i = 0; i < 7; ++i) {
        float sxA = xwA[i], sxB = xwB[i];         // uniform (SGPR)
        const float* pA = fmB + xoA[i];           // uniform pointers (SALU)
        const float* pB = fmB + xoB[i];
#pragma unroll
        for (int j = 0; j < 7; ++j) {
            float syA = ywA[j], syB = ywB[j];
            const float* q00 = pA + yoA[j];       // uniform + divergent tid -> saddr load
            const float* q10 = pB + yoA[j];
            const float* q01 = pA + yoB[j];
            const float* q11 = pB + yoB[j];
            float a00 = q00[tid];
            float a10 = q10[tid];
            float a01 = q01[tid];
            float a11 = q11[tid];
            float vx0 = sxA * a00 + sxB * a10;    // x-interp at y0
            float vx1 = sxA * a01 + sxB * a11;    // x-interp at y1
            row[i * 7 + j] = syA * vx0 + syB * vx1;
        }
    }

    // wave-local DS ordering: readback below reads rows written by lanes of THIS
    // wave only (cross-lane, same wave). Compiler can't see the cross-lane dep;
    // explicit wait + scheduling fence required (rule #18).
    asm volatile("s_waitcnt lgkmcnt(0)" ::: "memory");
    __builtin_amdgcn_sched_barrier(0);

    // ---- writeback: wave streams its slab; NON-TEMPORAL (bypass L2 alloc) ----
    int wv_id = tid >> 6;
    const vfloat4* s4 = (const vfloat4*)sOut + wv_id * 784;
    vfloat4* out4 = (vfloat4*)(out + (size_t)n * (CCH * G * G)) + wv_id * 784;
#pragma unroll
    for (int k = 0; k < 12; ++k) {
        __builtin_nontemporal_store(s4[k * 64 + lane], &out4[k * 64 + lane]);
    }
    if (lane < 16) {
        __builtin_nontemporal_store(s4[768 + lane], &out4[768 + lane]);  // 784 = 12*64+16
    }
}

// ---------------- fallback (round-2 kernel) if ws too small ----------------
__global__ __launch_bounds__(256) void roialign_fallback(
    const float* __restrict__ boxes,
    const float* __restrict__ f0, const float* __restrict__ f1,
    const float* __restrict__ f2, const float* __restrict__ f3,
    const float* __restrict__ f4, const float* __restrict__ f5,
    float* __restrict__ out, int total4)
{
    int t = blockIdx.x * blockDim.x + threadIdx.x;
    if (t >= total4) return;
    const int perN = CCH * G * G;
    int idx = t * 4;
    int n = idx / perN;
    int rem = idx - n * perN;
    float bx1 = boxes[n * 4 + 0], by1 = boxes[n * 4 + 1];
    float bx2 = boxes[n * 4 + 2], by2 = boxes[n * 4 + 3];
    float w = bx2 - bx1, h = by2 - by1;
    float avg = sqrtf(w * h);
    float lf = floorf((float)(NLVL - 1) + log2f(avg));
    lf = fminf(fmaxf(lf, 0.0f), (float)(NLVL - 1));
    int lvl = (int)lf;
    const float* fm;
    switch (lvl) {
        case 0: fm = f0; break;
        case 1: fm = f1; break;
        case 2: fm = f2; break;
        case 3: fm = f3; break;
        case 4: fm = f4; break;
        default: fm = f5; break;
    }
    int D = kD[lvl];
    float Dm1 = (float)(D - 1);
    float4 res;
    float* rp = &res.x;
#pragma unroll
    for (int k = 0; k < 4; ++k) {
        int e = rem + k;
        int j = e % G;
        int iq = e / G;
        int i = iq % G;
        int c = iq / G;
        float xr = fminf(fmaxf(bx1 + ((float)i * w) / 6.0f, 0.0f), 1.0f);
        float yr = fminf(fmaxf(by1 + ((float)j * h) / 6.0f, 0.0f), 1.0f);
        float ux = xr * Dm1, uy = yr * Dm1;
        float x0 = floorf(ux), y0 = floorf(uy);
        int ix0 = (int)x0, iy0 = (int)y0;
        float fx = ux - x0, fy = uy - y0;
        int ix1 = min(ix0 + 1, D - 1), iy1 = min(iy0 + 1, D - 1);
        const float* p = fm + c * D * D;
        float v00 = p[ix0 * D + iy0], v10 = p[ix1 * D + iy0];
        float v01 = p[ix0 * D + iy1], v11 = p[ix1 * D + iy1];
        float px0 = 1.0f - fx, py0 = 1.0f - fy;
        rp[k] = px0 * py0 * v00 + fx * py0 * v10 + px0 * fy * v01 + fx * fy * v11;
    }
    reinterpret_cast<float4*>(out)[t] = res;
}

extern "C" void kernel_launch(void* const* d_in, const int* in_sizes, int n_in,
                              void* d_out, int out_size, void* d_ws, size_t ws_size,
                              hipStream_t stream) {
    const float* boxes = (const float*)d_in[0];
    const float* f0 = (const float*)d_in[1];
    const float* f1 = (const float*)d_in[2];
    const float* f2 = (const float*)d_in[3];
    const float* f3 = (const float*)d_in[4];
    const float* f4 = (const float*)d_in[5];
    const float* f5 = (const float*)d_in[6];
    float* out = (float*)d_out;
    int N = in_sizes[0] / 4;

    if (ws_size >= (size_t)FMT_TOTAL * sizeof(float)) {
        float* fmT = (float*)d_ws;
        transpose_fmaps<<<(FMT_TOTAL + 255) / 256, 256, 0, stream>>>(
            f0, f1, f2, f3, f4, f5, fmT);
        roialign_main<<<N, 256, 0, stream>>>(boxes, fmT, out);
    } else {
        int total4 = out_size / 4;
        roialign_fallback<<<(total4 + 255) / 256, 256, 0, stream>>>(
            boxes, f0, f1, f2, f3, f4, f5, out, total4);
    }
}